// Round 3
// baseline (309.771 us; speedup 1.0000x reference)
//
#include <hip/hip_runtime.h>

typedef __bf16 bf16;
typedef __bf16 bf16x8 __attribute__((ext_vector_type(8)));
typedef float  f32x4  __attribute__((ext_vector_type(4)));
typedef unsigned int uint32;

#define BT 64  // batch elements per block

// ---- fixed problem geometry -> fixed bf16 workspace layout (element offsets) ----
#define N_E0 (339*128)
#define N_E1 (5825*128)
#define N_E2 (64*128)
#define N_W1 (256*128)
#define N_W2 (256*768)
#define N_F1 (256*256)
#define N_F2 256
#define O_E0 0
#define O_E1 (O_E0+N_E0)
#define O_E2 (O_E1+N_E1)
#define O_W1 (O_E2+N_E2)
#define O_W2 (O_W1+N_W1)
#define O_F1 (O_W2+N_W2)
#define O_F2 (O_F1+N_F1)
#define N_TOT (O_F2+N_F2)   // 1,092,352 bf16 elems = 2.18 MB in ws

static __device__ __forceinline__ f32x4 mfma16(bf16x8 a, bf16x8 b, f32x4 c) {
    return __builtin_amdgcn_mfma_f32_16x16x32_bf16(a, b, c, 0, 0, 0);
}

// fp32-vs-bf16 probe on w1 (dense, nonzero, |v|<=0.37):
// low 16 bits of each 32b word as bf16: exp>126 (|v|>=1) impossible for bf16 data,
// ~50%-per-word for fp32 mantissa bits. 64 words => error prob ~3e-20.
static __device__ __forceinline__ bool probe_fp32(const uint32* w1u, int tid, int* sF) {
    if (tid < 64) {
        uint32 e = (w1u[tid] >> 7) & 0xffu;
        if (e > 126u) atomicOr(sF, 1);
    }
    return true;
}

static __device__ __forceinline__ float ldf(const void* p, int i, bool fp32) {
    return fp32 ? ((const float*)p)[i] : (float)((const bf16*)p)[i];
}

// ---- pre-kernel: normalize all float arrays to bf16 in ws ----
__global__ __launch_bounds__(256)
void convert_all(const void* __restrict__ e0, const void* __restrict__ e1,
                 const void* __restrict__ e2, const void* __restrict__ w1,
                 const void* __restrict__ w2, const void* __restrict__ f1,
                 const void* __restrict__ f2, bf16* __restrict__ dst)
{
    __shared__ int sF;
    const int tid = threadIdx.x;
    if (tid == 0) sF = 0;
    __syncthreads();
    probe_fp32((const uint32*)w1, tid, &sF);
    __syncthreads();
    const bool fp32 = (sF != 0);

    for (unsigned i = blockIdx.x * 256u + tid; i < N_TOT; i += gridDim.x * 256u) {
        const void* src; unsigned off;
        if (i < O_E1)      { src = e0; off = i - O_E0; }
        else if (i < O_E2) { src = e1; off = i - O_E1; }
        else if (i < O_W1) { src = e2; off = i - O_E2; }
        else if (i < O_W2) { src = w1; off = i - O_W1; }
        else if (i < O_F1) { src = w2; off = i - O_W2; }
        else if (i < O_F2) { src = f1; off = i - O_F1; }
        else               { src = f2; off = i - O_F2; }
        dst[i] = fp32 ? (bf16)((const float*)src)[off] : ((const bf16*)src)[off];
    }
}

// ---- fully fused CoSTCo forward (reads normalized bf16 from ws) ----
__global__ __launch_bounds__(256, 2)
void costco_fused(const int* __restrict__ idx, const uint32* __restrict__ w1probe,
                  const bf16* __restrict__ wsb,
                  const void* __restrict__ b1, const void* __restrict__ b2,
                  const void* __restrict__ bfc1, const void* __restrict__ bfc2,
                  void* __restrict__ out)
{
    const bf16* emb0 = wsb + O_E0;
    const bf16* emb1 = wsb + O_E1;
    const bf16* emb2 = wsb + O_E2;
    const bf16* w1   = wsb + O_W1;
    const bf16* w2   = wsb + O_W2;
    const bf16* wfc1 = wsb + O_F1;
    const bf16* wfc2 = wsb + O_F2;

    __shared__ alignas(16) bf16 sX[192 * 136];   // A1: rows bm=b*3+m (192) x K=128
    __shared__ alignas(16) bf16 sH1[64 * 200];   // A2 chunk: rows b (64) x k_local=192
    __shared__ float sRed[64];
    __shared__ int sFlagI, sFlagF;
    bf16* sH2 = sX;                              // reuse: b (64) x d, stride 264

    const int tid  = threadIdx.x;
    const int wave = tid >> 6;
    const int lane = tid & 63;
    const int quad = lane >> 4;
    const int l15  = lane & 15;
    const int bbase = blockIdx.x * BT;

    // ---- dtype probes ----
    if (tid == 0) { sFlagI = 0; sFlagF = 0; }
    __syncthreads();
    if (idx[tid * 2 + 1] != 0) atomicOr(&sFlagI, 1);
    probe_fp32(w1probe, tid, &sFlagF);
    __syncthreads();
    const bool idx_is_i64 = (sFlagI == 0);
    const bool fp32 = (sFlagF != 0);

    // ---- gather embedding rows into sX: sX[bm][r] = emb_m[idx[b,m]][r] ----
    {
        const int sub = lane >> 5;
        const int col = lane & 31;        // 8B (4 bf16) units
        #pragma unroll 4
        for (int it = 0; it < 24; ++it) {
            int bm = wave * 48 + it * 2 + sub;          // 0..191
            int b  = bm / 3;
            int m  = bm - b * 3;
            long long p = (long long)(bbase + b) * 3 + m;
            long long ix = idx_is_i64 ? ((const long long*)idx)[p] : (long long)idx[p];
            long long dim = (m == 0 ? 339 : (m == 1 ? 5825 : 64));
            ix = ix < 0 ? 0 : (ix >= dim ? dim - 1 : ix);
            const bf16* src = (m == 0 ? emb0 : (m == 1 ? emb1 : emb2)) + ix * 128;
            *reinterpret_cast<uint2*>(&sX[bm * 136 + col * 4]) =
                *reinterpret_cast<const uint2*>(src + col * 4);
        }
    }
    __syncthreads();

    const f32x4 zero4 = {0.f, 0.f, 0.f, 0.f};

    f32x4 acc2[4][4];
    #pragma unroll
    for (int i = 0; i < 4; ++i)
        #pragma unroll
        for (int j = 0; j < 4; ++j) acc2[i][j] = zero4;

    for (int ci = 0; ci < 4; ++ci) {   // channel chunk [ci*64, ci*64+64)
        // ---- Stage A: h1[b][cl*3+m] = relu(x.W1^T+b1), waves split M ----
        bf16x8 bf1[4][4];
        float  b1v[4];
        #pragma unroll
        for (int nt = 0; nt < 4; ++nt) {
            int c = ci * 64 + nt * 16 + l15;
            b1v[nt] = ldf(b1, c, fp32);
            #pragma unroll
            for (int ks = 0; ks < 4; ++ks)
                bf1[nt][ks] = *reinterpret_cast<const bf16x8*>(w1 + c * 128 + ks * 32 + quad * 8);
        }
        #pragma unroll
        for (int mtl = 0; mtl < 3; ++mtl) {
            int mt = wave * 3 + mtl;
            f32x4 acc[4] = {zero4, zero4, zero4, zero4};
            #pragma unroll
            for (int ks = 0; ks < 4; ++ks) {
                bf16x8 af = *reinterpret_cast<const bf16x8*>(
                    &sX[(mt * 16 + l15) * 136 + ks * 32 + quad * 8]);
                #pragma unroll
                for (int nt = 0; nt < 4; ++nt)
                    acc[nt] = mfma16(af, bf1[nt][ks], acc[nt]);
            }
            #pragma unroll
            for (int nt = 0; nt < 4; ++nt) {
                int cl = nt * 16 + l15;
                #pragma unroll
                for (int r = 0; r < 4; ++r) {
                    int bm = mt * 16 + quad * 4 + r;
                    int b  = bm / 3;
                    int m  = bm - b * 3;
                    float v = acc[nt][r] + b1v[nt];
                    v = v > 0.f ? v : 0.f;
                    sH1[b * 200 + cl * 3 + m] = (bf16)v;
                }
            }
        }
        __syncthreads();

        // ---- Stage B partial: acc2 += h1chunk (64x192) . w2chunk, waves split N(d) ----
        #pragma unroll
        for (int ks = 0; ks < 6; ++ks) {
            bf16x8 af[4], bfr[4];
            #pragma unroll
            for (int mt = 0; mt < 4; ++mt)
                af[mt] = *reinterpret_cast<const bf16x8*>(
                    &sH1[(mt * 16 + l15) * 200 + ks * 32 + quad * 8]);
            #pragma unroll
            for (int nt = 0; nt < 4; ++nt) {
                int d = wave * 64 + nt * 16 + l15;
                bfr[nt] = *reinterpret_cast<const bf16x8*>(
                    w2 + d * 768 + ci * 192 + ks * 32 + quad * 8);
            }
            #pragma unroll
            for (int mt = 0; mt < 4; ++mt)
                #pragma unroll
                for (int nt = 0; nt < 4; ++nt)
                    acc2[mt][nt] = mfma16(af[mt], bfr[nt], acc2[mt][nt]);
        }
        __syncthreads();
    }

    // ---- h2 epilogue: bias+relu -> sH2 (aliases sX; all sX reads done) ----
    #pragma unroll
    for (int nt = 0; nt < 4; ++nt) {
        int d = wave * 64 + nt * 16 + l15;
        float b2v = ldf(b2, d, fp32);
        #pragma unroll
        for (int mt = 0; mt < 4; ++mt)
            #pragma unroll
            for (int r = 0; r < 4; ++r) {
                int b = mt * 16 + quad * 4 + r;
                float v = acc2[mt][nt][r] + b2v;
                v = v > 0.f ? v : 0.f;
                sH2[b * 264 + d] = (bf16)v;
            }
    }
    if (tid < 64) sRed[tid] = ldf(bfc2, 0, fp32);
    __syncthreads();

    // ---- Stage C: h3 = relu(h2 . Wfc1^T + bfc1), waves split N(e) ----
    f32x4 acc3[4][4];
    #pragma unroll
    for (int i = 0; i < 4; ++i)
        #pragma unroll
        for (int j = 0; j < 4; ++j) acc3[i][j] = zero4;

    #pragma unroll
    for (int ks = 0; ks < 8; ++ks) {
        bf16x8 af[4], bfr[4];
        #pragma unroll
        for (int mt = 0; mt < 4; ++mt)
            af[mt] = *reinterpret_cast<const bf16x8*>(
                &sH2[(mt * 16 + l15) * 264 + ks * 32 + quad * 8]);
        #pragma unroll
        for (int nt = 0; nt < 4; ++nt) {
            int e = wave * 64 + nt * 16 + l15;
            bfr[nt] = *reinterpret_cast<const bf16x8*>(wfc1 + e * 256 + ks * 32 + quad * 8);
        }
        #pragma unroll
        for (int mt = 0; mt < 4; ++mt)
            #pragma unroll
            for (int nt = 0; nt < 4; ++nt)
                acc3[mt][nt] = mfma16(af[mt], bfr[nt], acc3[mt][nt]);
    }

    // ---- Stage D: out = relu(h3 . wfc2 + bfc2) ----
    float w2v[4], bc1v[4];
    #pragma unroll
    for (int nt = 0; nt < 4; ++nt) {
        int e = wave * 64 + nt * 16 + l15;
        w2v[nt]  = (float)wfc2[e];
        bc1v[nt] = ldf(bfc1, e, fp32);
    }
    #pragma unroll
    for (int mt = 0; mt < 4; ++mt)
        #pragma unroll
        for (int r = 0; r < 4; ++r) {
            float p = 0.f;
            #pragma unroll
            for (int nt = 0; nt < 4; ++nt) {
                float h = acc3[mt][nt][r] + bc1v[nt];
                h = h > 0.f ? h : 0.f;
                p += h * w2v[nt];
            }
            p += __shfl_xor(p, 1, 64);
            p += __shfl_xor(p, 2, 64);
            p += __shfl_xor(p, 4, 64);
            p += __shfl_xor(p, 8, 64);
            if (l15 == 0) atomicAdd(&sRed[mt * 16 + quad * 4 + r], p);
        }
    __syncthreads();

    if (tid < 64) {
        float v = sRed[tid];
        v = v > 0.f ? v : 0.f;
        if (fp32) ((float*)out)[bbase + tid] = v;
        else      ((bf16*)out)[bbase + tid] = (bf16)v;
    }
}

extern "C" void kernel_launch(void* const* d_in, const int* in_sizes, int n_in,
                              void* d_out, int out_size, void* d_ws, size_t ws_size,
                              hipStream_t stream) {
    const int* idx = (const int*)d_in[0];
    bf16* wsb = (bf16*)d_ws;

    hipLaunchKernelGGL(convert_all, dim3(1024), dim3(256), 0, stream,
                       d_in[1], d_in[2], d_in[3], d_in[4], d_in[6],
                       d_in[8], d_in[10], wsb);

    const int B = 131072;
    hipLaunchKernelGGL(costco_fused, dim3(B / BT), dim3(256), 0, stream,
                       idx, (const uint32*)d_in[4], wsb,
                       d_in[5], d_in[7], d_in[9], d_in[11], d_out);
}

// Round 4
// 265.538 us; speedup vs baseline: 1.1666x; 1.1666x over previous
//
#include <hip/hip_runtime.h>

typedef __bf16 bf16;
typedef __bf16 bf16x4 __attribute__((ext_vector_type(4)));
typedef __bf16 bf16x8 __attribute__((ext_vector_type(8)));
typedef float  f32x4  __attribute__((ext_vector_type(4)));
typedef unsigned int uint32;

#define BT 64

// ---- bf16 workspace layout (element offsets) ----
#define N_E0 (339*128)
#define N_E1 (5825*128)
#define N_E2 (64*128)
#define N_W1 (256*128)
#define N_W2 (256*768)
#define N_F1 (256*256)
#define N_F2 256
#define O_E0 0
#define O_E1 (O_E0+N_E0)
#define O_E2 (O_E1+N_E1)
#define O_W1 (O_E2+N_E2)
#define O_W2 (O_W1+N_W1)   // holds w2 TRANSPOSED: [d][m*256+c]
#define O_F1 (O_W2+N_W2)
#define O_F2 (O_F1+N_F1)
#define N_TOT (O_F2+N_F2)  // 1,092,352 bf16

#define BYTES_BF16 ((size_t)N_TOT*2)
#define OFF_FLOAT  BYTES_BF16              // f32: b1(256) b2(256) bfc1(256) bfc2(1)
#define OFF_FLAG   (OFF_FLOAT + 772*4)     // int out-dtype flag
#define OFF_IDX    (OFF_FLAG + 16)         // int32 idx (131072*3)
#define N_IDX      (131072*3)

static __device__ __forceinline__ f32x4 mfma16(bf16x8 a, bf16x8 b, f32x4 c) {
    return __builtin_amdgcn_mfma_f32_16x16x32_bf16(a, b, c, 0, 0, 0);
}

// ---- one-time normalization: weights->bf16 (w2 transposed), biases->f32,
// ---- idx->clamped int32, out-dtype flag. Probes are deterministic:
// fp32 probe: low-16-of-word as bf16 exp>126 impossible for |w1|<=0.37 bf16 data.
// i64 probe: 256 odd words all zero <=> int64.
__global__ __launch_bounds__(256)
void convert_all(const void* __restrict__ e0, const void* __restrict__ e1,
                 const void* __restrict__ e2, const void* __restrict__ w1r,
                 const void* __restrict__ b1r, const void* __restrict__ w2r,
                 const void* __restrict__ b2r, const void* __restrict__ f1r,
                 const void* __restrict__ fc1br, const void* __restrict__ f2r,
                 const void* __restrict__ fc2br, const void* __restrict__ idxr,
                 bf16* __restrict__ wsb, float* __restrict__ wsf,
                 int* __restrict__ flagp, int* __restrict__ idx32)
{
    __shared__ int sF, sI;
    const int tid = threadIdx.x;
    if (tid == 0) { sF = 0; sI = 0; }
    __syncthreads();
    if (tid < 64) {
        uint32 e = (((const uint32*)w1r)[tid] >> 7) & 0xffu;
        if (e > 126u) atomicOr(&sF, 1);
    }
    if (((const uint32*)idxr)[tid * 2 + 1] != 0) atomicOr(&sI, 1);
    __syncthreads();
    const bool fp32 = (sF != 0);
    const bool i64  = (sI == 0);
    if (blockIdx.x == 0 && tid == 0) *flagp = fp32 ? 1 : 0;

    const unsigned VT = N_TOT + 769u + N_IDX;
    for (unsigned i = blockIdx.x * 256u + tid; i < VT; i += gridDim.x * 256u) {
        if (i < N_TOT) {
            const void* src; unsigned off;
            if (i < O_E1)      { src = e0;  off = i; }
            else if (i < O_E2) { src = e1;  off = i - O_E1; }
            else if (i < O_W1) { src = e2;  off = i - O_E2; }
            else if (i < O_W2) { src = w1r; off = i - O_W1; }
            else if (i < O_F1) {                    // w2t[d][m*256+c] = w2[d][c][m]
                unsigned l = i - O_W2;
                unsigned d = l / 768u, r = l - d * 768u;
                unsigned m = r >> 8, c = r & 255u;
                src = w2r; off = d * 768u + c * 3u + m;
            }
            else if (i < O_F2) { src = f1r; off = i - O_F1; }
            else               { src = f2r; off = i - O_F2; }
            wsb[i] = fp32 ? (bf16)((const float*)src)[off] : ((const bf16*)src)[off];
        } else if (i < N_TOT + 769u) {
            unsigned j = i - N_TOT;
            const void* src; unsigned off;
            if (j < 256u)      { src = b1r;   off = j; }
            else if (j < 512u) { src = b2r;   off = j - 256u; }
            else if (j < 768u) { src = fc1br; off = j - 512u; }
            else               { src = fc2br; off = 0; }
            wsf[j] = fp32 ? ((const float*)src)[off] : (float)((const bf16*)src)[off];
        } else {
            unsigned k = i - N_TOT - 769u;
            long long v = i64 ? ((const long long*)idxr)[k]
                              : (long long)((const int*)idxr)[k];
            unsigned m = k % 3u;
            long long dim = (m == 0 ? 339 : (m == 1 ? 5825 : 64));
            v = v < 0 ? 0 : (v >= dim ? dim - 1 : v);
            idx32[k] = (int)v;
        }
    }
}

// ---- fused forward. Per block: 64 batch rows. 51.5 KB LDS -> 3 blocks/CU. ----
__global__ __launch_bounds__(256, 3)
void costco_fused(const bf16* __restrict__ wsb, const float* __restrict__ wsf,
                  const int* __restrict__ flagp, const int* __restrict__ idx32,
                  void* __restrict__ out)
{
    __shared__ alignas(16) bf16 sX[64 * 136];   // mode-m gathered rows, 17.4 KB
    __shared__ alignas(16) bf16 sH1[64 * 264];  // h1_m / h2, 33.8 KB
    __shared__ float sRed[64];

    const bf16* w1   = wsb + O_W1;
    const bf16* w2t  = wsb + O_W2;
    const bf16* wfc1 = wsb + O_F1;
    const bf16* wfc2 = wsb + O_F2;
    const float* fb1  = wsf;
    const float* fb2  = wsf + 256;
    const float* fbc1 = wsf + 512;
    const float  bfc2v = wsf[768];
    const int fp32out = *flagp;

    const int tid  = threadIdx.x;
    const int wave = tid >> 6;
    const int lane = tid & 63;
    const int quad = lane >> 4;
    const int l15  = lane & 15;
    const int bbase = blockIdx.x * BT;

    auto do_gather = [&](int m) {
        const int row = tid >> 2;
        const int seg = tid & 3;
        int ix = idx32[(bbase + row) * 3 + m];
        const bf16* src = wsb + (m == 0 ? O_E0 : (m == 1 ? O_E1 : O_E2))
                          + (size_t)ix * 128 + seg * 32;
        const uint4* s4 = reinterpret_cast<const uint4*>(src);
        uint4* d4 = reinterpret_cast<uint4*>(&sX[row * 136 + seg * 32]);
        #pragma unroll
        for (int u = 0; u < 4; ++u) d4[u] = s4[u];
    };

    if (tid < 64) sRed[tid] = bfc2v;
    do_gather(0);
    __syncthreads();

    const f32x4 zero4 = {0.f, 0.f, 0.f, 0.f};
    f32x4 acc2[4][4];
    #pragma unroll
    for (int i = 0; i < 4; ++i)
        #pragma unroll
        for (int j = 0; j < 4; ++j) acc2[i][j] = zero4;

    for (int m = 0; m < 3; ++m) {
        // Stage A: h1_m = relu(x_m W1^T + b1). A=w1 rows c (M), B=x rows b (N).
        // D rows=c (4/lane contiguous) -> vectorized b64 epilogue into sH1[b][c].
        #pragma unroll
        for (int mtl = 0; mtl < 4; ++mtl) {
            int mt = wave * 4 + mtl;              // c-tile 0..15
            int c  = mt * 16 + l15;
            bf16x8 aw[4];
            #pragma unroll
            for (int ks = 0; ks < 4; ++ks)
                aw[ks] = *reinterpret_cast<const bf16x8*>(w1 + c * 128 + ks * 32 + quad * 8);
            const float4 bv = *reinterpret_cast<const float4*>(fb1 + mt * 16 + quad * 4);
            #pragma unroll
            for (int nt = 0; nt < 4; ++nt) {
                f32x4 acc = zero4;
                #pragma unroll
                for (int ks = 0; ks < 4; ++ks) {
                    bf16x8 xb = *reinterpret_cast<const bf16x8*>(
                        &sX[(nt * 16 + l15) * 136 + ks * 32 + quad * 8]);
                    acc = mfma16(aw[ks], xb, acc);
                }
                bf16x4 hv;
                hv[0] = (bf16)fmaxf(acc[0] + bv.x, 0.f);
                hv[1] = (bf16)fmaxf(acc[1] + bv.y, 0.f);
                hv[2] = (bf16)fmaxf(acc[2] + bv.z, 0.f);
                hv[3] = (bf16)fmaxf(acc[3] + bv.w, 0.f);
                *reinterpret_cast<bf16x4*>(
                    &sH1[(nt * 16 + l15) * 264 + mt * 16 + quad * 4]) = hv;
            }
        }
        __syncthreads();
        if (m < 2) do_gather(m + 1);   // overlaps with stage B below

        // Stage B: acc2 += h1_m (64x256) . w2t_m^T, waves split N(d)
        #pragma unroll
        for (int ks = 0; ks < 8; ++ks) {
            bf16x8 af[4], bfr[4];
            #pragma unroll
            for (int mt = 0; mt < 4; ++mt)
                af[mt] = *reinterpret_cast<const bf16x8*>(
                    &sH1[(mt * 16 + l15) * 264 + ks * 32 + quad * 8]);
            #pragma unroll
            for (int nt = 0; nt < 4; ++nt) {
                int d = wave * 64 + nt * 16 + l15;
                bfr[nt] = *reinterpret_cast<const bf16x8*>(
                    w2t + d * 768 + m * 256 + ks * 32 + quad * 8);
            }
            #pragma unroll
            for (int mt = 0; mt < 4; ++mt)
                #pragma unroll
                for (int nt = 0; nt < 4; ++nt)
                    acc2[mt][nt] = mfma16(af[mt], bfr[nt], acc2[mt][nt]);
        }
        __syncthreads();
    }

    // h2 epilogue: bias+relu -> sH1 reused as sH2[b][d]
    #pragma unroll
    for (int nt = 0; nt < 4; ++nt) {
        int d = wave * 64 + nt * 16 + l15;
        float b2v = fb2[d];
        #pragma unroll
        for (int mt = 0; mt < 4; ++mt)
            #pragma unroll
            for (int r = 0; r < 4; ++r) {
                int b = mt * 16 + quad * 4 + r;
                sH1[b * 264 + d] = (bf16)fmaxf(acc2[mt][nt][r] + b2v, 0.f);
            }
    }
    __syncthreads();

    // Stage C: h3 = relu(h2 Wfc1^T + bfc1), waves split N(e)
    f32x4 acc3[4][4];
    #pragma unroll
    for (int i = 0; i < 4; ++i)
        #pragma unroll
        for (int j = 0; j < 4; ++j) acc3[i][j] = zero4;
    #pragma unroll
    for (int ks = 0; ks < 8; ++ks) {
        bf16x8 af[4], bfr[4];
        #pragma unroll
        for (int mt = 0; mt < 4; ++mt)
            af[mt] = *reinterpret_cast<const bf16x8*>(
                &sH1[(mt * 16 + l15) * 264 + ks * 32 + quad * 8]);
        #pragma unroll
        for (int nt = 0; nt < 4; ++nt) {
            int e = wave * 64 + nt * 16 + l15;
            bfr[nt] = *reinterpret_cast<const bf16x8*>(wfc1 + e * 256 + ks * 32 + quad * 8);
        }
        #pragma unroll
        for (int mt = 0; mt < 4; ++mt)
            #pragma unroll
            for (int nt = 0; nt < 4; ++nt)
                acc3[mt][nt] = mfma16(af[mt], bfr[nt], acc3[mt][nt]);
    }

    // Stage D: out = relu(h3 . wfc2 + bfc2)
    float wv[4], bc[4];
    #pragma unroll
    for (int nt = 0; nt < 4; ++nt) {
        int e = wave * 64 + nt * 16 + l15;
        wv[nt] = (float)wfc2[e];
        bc[nt] = fbc1[e];
    }
    #pragma unroll
    for (int mt = 0; mt < 4; ++mt)
        #pragma unroll
        for (int r = 0; r < 4; ++r) {
            float p = 0.f;
            #pragma unroll
            for (int nt = 0; nt < 4; ++nt) {
                float h = acc3[mt][nt][r] + bc[nt];
                p += fmaxf(h, 0.f) * wv[nt];
            }
            p += __shfl_xor(p, 1, 64);
            p += __shfl_xor(p, 2, 64);
            p += __shfl_xor(p, 4, 64);
            p += __shfl_xor(p, 8, 64);
            if (l15 == 0) atomicAdd(&sRed[mt * 16 + quad * 4 + r], p);
        }
    __syncthreads();

    if (tid < 64) {
        float v = fmaxf(sRed[tid], 0.f);
        if (fp32out) ((float*)out)[bbase + tid] = v;
        else         ((bf16*)out)[bbase + tid] = (bf16)v;
    }
}

extern "C" void kernel_launch(void* const* d_in, const int* in_sizes, int n_in,
                              void* d_out, int out_size, void* d_ws, size_t ws_size,
                              hipStream_t stream) {
    char* ws = (char*)d_ws;
    bf16*  wsb   = (bf16*)ws;
    float* wsf   = (float*)(ws + OFF_FLOAT);
    int*   flagp = (int*)(ws + OFF_FLAG);
    int*   idx32 = (int*)(ws + OFF_IDX);

    hipLaunchKernelGGL(convert_all, dim3(1024), dim3(256), 0, stream,
                       d_in[1], d_in[2], d_in[3], d_in[4], d_in[5], d_in[6],
                       d_in[7], d_in[8], d_in[9], d_in[10], d_in[11], d_in[0],
                       wsb, wsf, flagp, idx32);

    const int B = 131072;
    hipLaunchKernelGGL(costco_fused, dim3(B / BT), dim3(256), 0, stream,
                       wsb, wsf, flagp, idx32, d_out);
}